// Round 8
// baseline (4225.468 us; speedup 1.0000x reference)
//
#include <hip/hip_runtime.h>
#include <hip/hip_bf16.h>

typedef __hip_bfloat16 bf16;
typedef __attribute__((ext_vector_type(8))) short short8;
typedef __attribute__((ext_vector_type(4))) float float4v;

#define BATCH 8
#define SEQ   1568            // 14*14*8 tokens per batch = 49 segments x 32
#define M_TOK (BATCH*SEQ)     // 12544
#define DM    768
#define DI    1536
#define DS    16
#define DTR   48
#define NCLS  1000
#define LAYERS 4
#define NSEG  49
#define SEGL  32

__device__ __forceinline__ float b2f(bf16 v){ return __bfloat162float(v); }
__device__ __forceinline__ bf16  f2b(float v){ return __float2bfloat16(v); }
__device__ __forceinline__ float us2f(unsigned short u){
    unsigned v = ((unsigned)u) << 16; float f; __builtin_memcpy(&f, &v, 4); return f;
}

// ---------------------------------------------------------------- dtype probe
__global__ void detect_dtype(const unsigned short* __restrict__ probe, unsigned* __restrict__ flag)
{
    if (threadIdx.x == 0 && blockIdx.x == 0) flag[0] = (probe[0] == 0) ? 1u : 0u;  // 1 = fp32
}

__global__ __launch_bounds__(256)
void to_bf16(const unsigned* __restrict__ flag, const void* __restrict__ src,
             bf16* __restrict__ dst, int n)
{
    int i = blockIdx.x*256 + threadIdx.x;
    if (i >= n) return;
    dst[i] = flag[0] ? f2b(((const float*)src)[i]) : ((const bf16*)src)[i];
}

__global__ __launch_bounds__(256)
void to_f32(const unsigned* __restrict__ flag, const void* __restrict__ src,
            float* __restrict__ dst, int n)
{
    int i = blockIdx.x*256 + threadIdx.x;
    if (i >= n) return;
    dst[i] = flag[0] ? ((const float*)src)[i] : b2f(((const bf16*)src)[i]);
}

// ---------------------------------------------------------------- gather patches (per batch-group)
__global__ __launch_bounds__(256)
void gather_patches(const bf16* __restrict__ x, bf16* __restrict__ Ap, int b0)
{
    size_t idx = (size_t)blockIdx.x*256 + threadIdx.x;
    int i = (int)(idx & 255);
    int m = (int)(idx >> 8);
    int b = b0 + m / SEQ, s = m % SEQ;
    int hw = s >> 3, c = s & 7;
    int h = hw / 14, w = hw % 14;
    int p = i >> 4, q = i & 15;
    Ap[idx] = x[(((size_t)(b*8 + c)*224) + h*16 + p)*224 + w*16 + q];
}

// ---------------------------------------------------------------- MFMA GEMM (128x128 tile, BK=32)
__global__ __launch_bounds__(256)
void gemm_mfma(const bf16* __restrict__ A, int lda,
               const bf16* __restrict__ W, int ldw,
               float* __restrict__ Cf, bf16* __restrict__ Cb, int ldc,
               const float* __restrict__ bias, const float* __restrict__ chan,
               int M, int N, int K, int epi)
{
    __shared__ short As[128*40];
    __shared__ short Bs[128*40];
    int tid  = threadIdx.x;
    int m0   = blockIdx.x*128, n0 = blockIdx.y*128;
    int lane = tid & 63, wv = tid >> 6;
    int wm = (wv >> 1)*64, wn = (wv & 1)*64;
    int l15 = lane & 15, quad = lane >> 4;

    float4v acc[4][4];
    #pragma unroll
    for (int i = 0; i < 4; ++i)
        #pragma unroll
        for (int j = 0; j < 4; ++j) acc[i][j] = (float4v){0.f,0.f,0.f,0.f};

    const short8 zv8 = {0,0,0,0,0,0,0,0};
    for (int k0 = 0; k0 < K; k0 += 32) {
        #pragma unroll
        for (int u = 0; u < 2; ++u) {
            int c   = tid*2 + u;
            int row = c >> 2, ch = c & 3;
            bool kok = (k0 + ch*8 + 8) <= K;
            short8 va = (kok && m0 + row < M)
                ? *(const short8*)((const short*)A + (size_t)(m0+row)*lda + k0 + ch*8) : zv8;
            *(short8*)(As + row*40 + ch*8) = va;
            short8 vb = (kok && n0 + row < N)
                ? *(const short8*)((const short*)W + (size_t)(n0+row)*ldw + k0 + ch*8) : zv8;
            *(short8*)(Bs + row*40 + ch*8) = vb;
        }
        __syncthreads();
        short8 av[4], bv[4];
        #pragma unroll
        for (int i = 0; i < 4; ++i) av[i] = *(const short8*)(As + (wm + i*16 + l15)*40 + quad*8);
        #pragma unroll
        for (int j = 0; j < 4; ++j) bv[j] = *(const short8*)(Bs + (wn + j*16 + l15)*40 + quad*8);
        #pragma unroll
        for (int i = 0; i < 4; ++i)
            #pragma unroll
            for (int j = 0; j < 4; ++j)
                acc[i][j] = __builtin_amdgcn_mfma_f32_16x16x32_bf16(av[i], bv[j], acc[i][j], 0, 0, 0);
        __syncthreads();
    }

    #pragma unroll
    for (int i = 0; i < 4; ++i) {
        #pragma unroll
        for (int j = 0; j < 4; ++j) {
            int gn = n0 + wn + j*16 + l15;
            if (gn >= N) continue;
            #pragma unroll
            for (int r = 0; r < 4; ++r) {
                int gm = m0 + wm + i*16 + quad*4 + r;
                if (gm >= M) continue;
                float v = acc[i][j][r];
                size_t off = (size_t)gm*ldc + gn;
                if (epi == 0)      Cb[off] = f2b(v);
                else if (epi == 1) {
                    v += bias[gn];
                    v = (v > 20.f) ? v : log1pf(__expf(v));
                    Cb[off] = f2b(v);
                }
                else if (epi == 2) Cf[off] += v;
                else               Cf[off] = v + bias[gn] + chan[(size_t)(gm & 7)*N + gn];
            }
        }
    }
}

// ---------------------------------------------------------------- LayerNorm 768 (fp32 in, bf16 out)
__global__ __launch_bounds__(256)
void ln768(const float* __restrict__ X, const float* __restrict__ w,
           const float* __restrict__ bb, bf16* __restrict__ out)
{
    __shared__ float red[8];
    size_t t = blockIdx.x;
    const float* x = X + t*DM;
    float v[3]; float s = 0.f, s2 = 0.f;
    #pragma unroll
    for (int r = 0; r < 3; ++r) {
        v[r] = x[threadIdx.x + 256*r];
        s += v[r]; s2 += v[r]*v[r];
    }
    #pragma unroll
    for (int o = 32; o; o >>= 1) { s += __shfl_down(s, o, 64); s2 += __shfl_down(s2, o, 64); }
    if ((threadIdx.x & 63) == 0) { red[threadIdx.x >> 6] = s; red[(threadIdx.x >> 6) + 4] = s2; }
    __syncthreads();
    s  = red[0]+red[1]+red[2]+red[3];
    s2 = red[4]+red[5]+red[6]+red[7];
    float mu  = s * (1.f/DM);
    float inv = rsqrtf(fmaxf(s2*(1.f/DM) - mu*mu, 0.f) + 1e-5f);
    #pragma unroll
    for (int r = 0; r < 3; ++r) {
        int i = threadIdx.x + 256*r;
        out[t*DM + i] = f2b((v[r]-mu)*inv*w[i] + bb[i]);
    }
}

// ---------------------------------------------------------------- causal depthwise conv (k=4) + silu
__global__ __launch_bounds__(256)
void conv_silu(const bf16* __restrict__ xh, const float* __restrict__ cw,
               const float* __restrict__ cb, bf16* __restrict__ xc)
{
    size_t idx = (size_t)blockIdx.x*256 + threadIdx.x;
    int d = (int)(idx % DI);
    int m = (int)(idx / DI);
    int b = m / SEQ, t = m % SEQ;
    float acc = cb[d];
    #pragma unroll
    for (int k = 0; k < 4; ++k) {
        int tt = t + k - 3;
        if (tt >= 0)
            acc += b2f(xh[(size_t)(b*SEQ + tt)*DI + d]) * cw[d*4 + k];
    }
    float sig = 1.f/(1.f + __expf(-acc));
    xc[idx] = f2b(acc*sig);
}

// ================================================================ chunked selective scan
// h_t = exp(dt_t*A) h_{t-1} + dt_t x_t B_t ;  y_t = <h_t, C_t> + D x_t
// Over a segment: h_out = exp2(A2*sum_dt) h_in + B_seg, B_seg by 32-step local recurrence.
// seg buffer layout: [b][si][d][n] fp32;  sumdt: [b][si][d] fp32.

// ---- pass 1: per-segment summaries (B_seg, sum_dt). 1 wave per (b,dblk,si). ----
__global__ __launch_bounds__(64)
void scan_p1(const bf16* __restrict__ dt, const bf16* __restrict__ x,
             const bf16* __restrict__ dbc, const float* __restrict__ Alog,
             float* __restrict__ seg, float* __restrict__ sumdt)
{
    __shared__ float dtT[16][36], xT[16][36];   // [dl][t]
    __shared__ float Bsh[32][20];               // [t][n] (pad 20)
    int si = blockIdx.x % NSEG;
    int tt = blockIdx.x / NSEG;
    int dblk = tt % (DI/16);
    int b = tt / (DI/16);
    int d0 = dblk*16;
    int tid = threadIdx.x;
    int s = tid & 3, dl = tid >> 2, d = d0 + dl;

    float4v Av = *(const float4v*)&Alog[(size_t)d*DS + s*4];
    float A2[4], S[4];
    #pragma unroll
    for (int k = 0; k < 4; ++k) { A2[k] = -__expf(Av[k]) * 1.44269504f; S[k] = 0.f; }

    int r = tid & 31, p = tid >> 5;
    size_t rowm = (size_t)(b*SEQ + si*SEGL + r);
    short8 vdt = *(const short8*)((const unsigned short*)dt  + rowm*DI + d0 + p*8);
    short8 vx  = *(const short8*)((const unsigned short*)x   + rowm*DI + d0 + p*8);
    short8 vB  = *(const short8*)((const unsigned short*)dbc + rowm*80 + DTR + p*8);
    #pragma unroll
    for (int i = 0; i < 8; ++i) {
        dtT[p*8+i][r] = us2f((unsigned short)vdt[i]);
        xT [p*8+i][r] = us2f((unsigned short)vx[i]);
        Bsh[r][p*8+i] = us2f((unsigned short)vB[i]);
    }
    __syncthreads();

    float sdt = 0.f;
    #pragma unroll
    for (int t4 = 0; t4 < 8; ++t4) {
        float4v dv  = *(const float4v*)&dtT[dl][t4*4];
        float4v xv4 = *(const float4v*)&xT [dl][t4*4];
        #pragma unroll
        for (int jq = 0; jq < 4; ++jq) {
            int j = t4*4 + jq;
            float dtv = dv[jq], xv = xv4[jq];
            float dtx = dtv*xv;
            sdt += dtv;
            float4v Bv = *(const float4v*)&Bsh[j][s*4];
            #pragma unroll
            for (int k = 0; k < 4; ++k)
                S[k] = exp2f(dtv*A2[k])*S[k] + dtx*Bv[k];
        }
    }
    size_t o = ((size_t)(b*NSEG + si)*DI + d)*DS + s*4;
    *(float4v*)&seg[o] = (float4v){S[0], S[1], S[2], S[3]};
    if (s == 0) sumdt[(size_t)(b*NSEG + si)*DI + d] = sdt;
}

// ---- pass 2: 49-step scan over summaries; in-place (seg[si] becomes h_pre[si]) ----
__global__ __launch_bounds__(256)
void scan_p2(const float* __restrict__ Alog, const float* __restrict__ sumdt,
             float* seg)
{
    int dblk = blockIdx.x % (DI/16), b = blockIdx.x / (DI/16);
    int n = threadIdx.x & 15, dl = threadIdx.x >> 4;
    int d = dblk*16 + dl;
    float A2 = -__expf(Alog[(size_t)d*DS + n]) * 1.44269504f;
    float h = 0.f;
    for (int si = 0; si < NSEG; ++si) {
        float sdt = sumdt[(size_t)(b*NSEG + si)*DI + d];
        size_t o = ((size_t)(b*NSEG + si)*DI + d)*DS + n;
        float Bv = seg[o];
        seg[o] = h;                         // h entering segment si
        h = exp2f(A2*sdt)*h + Bv;
    }
}

// ---- pass 3: within-segment scan from h_pre, emit y. 1 wave per (b,dblk,si). ----
__global__ __launch_bounds__(64)
void scan_p3(const bf16* __restrict__ dt, const bf16* __restrict__ x,
             const bf16* __restrict__ dbc, const float* __restrict__ Alog,
             const float* __restrict__ Dpar, const float* __restrict__ seg,
             bf16* __restrict__ y)
{
    __shared__ float dtT[16][36], xT[16][36];
    __shared__ float Bsh[32][20], Csh[32][20];
    __shared__ bf16  ys[32][16];
    int si = blockIdx.x % NSEG;
    int tt = blockIdx.x / NSEG;
    int dblk = tt % (DI/16);
    int b = tt / (DI/16);
    int d0 = dblk*16;
    int tid = threadIdx.x;
    int s = tid & 3, dl = tid >> 2, d = d0 + dl;

    float4v Av = *(const float4v*)&Alog[(size_t)d*DS + s*4];
    float A2[4], h[4];
    float4v hv = *(const float4v*)&seg[((size_t)(b*NSEG + si)*DI + d)*DS + s*4];
    #pragma unroll
    for (int k = 0; k < 4; ++k) { A2[k] = -__expf(Av[k]) * 1.44269504f; h[k] = hv[k]; }
    float Dv = Dpar[d];

    int r = tid & 31, p = tid >> 5;
    size_t rowm = (size_t)(b*SEQ + si*SEGL + r);
    short8 vdt = *(const short8*)((const unsigned short*)dt  + rowm*DI + d0 + p*8);
    short8 vx  = *(const short8*)((const unsigned short*)x   + rowm*DI + d0 + p*8);
    short8 vB  = *(const short8*)((const unsigned short*)dbc + rowm*80 + DTR + p*8);
    short8 vC  = *(const short8*)((const unsigned short*)dbc + rowm*80 + DTR + DS + p*8);
    #pragma unroll
    for (int i = 0; i < 8; ++i) {
        dtT[p*8+i][r] = us2f((unsigned short)vdt[i]);
        xT [p*8+i][r] = us2f((unsigned short)vx[i]);
        Bsh[r][p*8+i] = us2f((unsigned short)vB[i]);
        Csh[r][p*8+i] = us2f((unsigned short)vC[i]);
    }
    __syncthreads();

    #pragma unroll
    for (int half = 0; half < 2; ++half) {
        float pr[16];
        #pragma unroll
        for (int t4 = 0; t4 < 4; ++t4) {
            float4v dv  = *(const float4v*)&dtT[dl][half*16 + t4*4];
            float4v xv4 = *(const float4v*)&xT [dl][half*16 + t4*4];
            #pragma unroll
            for (int jq = 0; jq < 4; ++jq) {
                int j = t4*4 + jq;
                int tgl = half*16 + j;
                float dtv = dv[jq], xv = xv4[jq];
                float dtx = dtv*xv;
                float4v Bv = *(const float4v*)&Bsh[tgl][s*4];
                float4v Cv = *(const float4v*)&Csh[tgl][s*4];
                float pp = 0.f;
                #pragma unroll
                for (int k = 0; k < 4; ++k) {
                    h[k] = exp2f(dtv*A2[k])*h[k] + dtx*Bv[k];
                    pp += h[k]*Cv[k];
                }
                if (s == 0) pp += Dv*xv;
                pr[j] = pp;
            }
        }
        #pragma unroll
        for (int j = 0; j < 16; ++j) {
            float pp = pr[j];
            pp += __shfl_xor(pp, 1, 4);
            pp += __shfl_xor(pp, 2, 4);
            if (s == 0) ys[half*16 + j][dl] = f2b(pp);
        }
    }
    __syncthreads();
    short8 vy = *(const short8*)((const unsigned short*)&ys[r][0] + p*8);
    *(short8*)((unsigned short*)y + rowm*DI + d0 + p*8) = vy;
}

// ---------------------------------------------------------------- LN(1536) * silu(z) gate
__global__ __launch_bounds__(256)
void gate_ln(const bf16* __restrict__ y, const bf16* __restrict__ z,
             const float* __restrict__ w, const float* __restrict__ bb,
             bf16* __restrict__ out)
{
    __shared__ float red[8];
    size_t t = blockIdx.x;
    const bf16* yy = y + t*DI;
    const bf16* zz = z + t*DI;
    float v[6]; float s = 0.f, s2 = 0.f;
    #pragma unroll
    for (int r = 0; r < 6; ++r) {
        v[r] = b2f(yy[threadIdx.x + 256*r]);
        s += v[r]; s2 += v[r]*v[r];
    }
    #pragma unroll
    for (int o = 32; o; o >>= 1) { s += __shfl_down(s, o, 64); s2 += __shfl_down(s2, o, 64); }
    if ((threadIdx.x & 63) == 0) { red[threadIdx.x >> 6] = s; red[(threadIdx.x >> 6) + 4] = s2; }
    __syncthreads();
    s  = red[0]+red[1]+red[2]+red[3];
    s2 = red[4]+red[5]+red[6]+red[7];
    float mu  = s * (1.f/DI);
    float inv = rsqrtf(fmaxf(s2*(1.f/DI) - mu*mu, 0.f) + 1e-5f);
    #pragma unroll
    for (int r = 0; r < 6; ++r) {
        int i = threadIdx.x + 256*r;
        float zv = b2f(zz[i]);
        float sig = 1.f/(1.f + __expf(-zv));
        out[t*DI + i] = f2b(((v[r]-mu)*inv*w[i] + bb[i]) * (zv*sig));
    }
}

// ---------------------------------------------------------------- mean pool over tokens
__global__ __launch_bounds__(256)
void pool_kernel(const bf16* __restrict__ hf, float* __restrict__ pooled)
{
    int idx = blockIdx.x*256 + threadIdx.x;
    int b = idx / DM, dm = idx % DM;
    const bf16* p = hf + (size_t)b*SEQ*DM + dm;
    float s = 0.f;
    for (int t = 0; t < SEQ; ++t) s += b2f(p[(size_t)t*DM]);
    pooled[idx] = s * (1.f/SEQ);
}

// ---------------------------------------------------------------- classifier head
__global__ __launch_bounds__(256)
void head_kernel(const unsigned* __restrict__ flag,
                 const float* __restrict__ pooled, const bf16* __restrict__ hw,
                 const float* __restrict__ hb, void* __restrict__ out)
{
    int idx = blockIdx.x*256 + threadIdx.x;
    if (idx >= BATCH*NCLS) return;
    int b = idx & 7, n = idx >> 3;
    const float* p = pooled + b*DM;
    const unsigned short* w = (const unsigned short*)hw + (size_t)n*DM;
    float acc = hb[n];
    for (int k = 0; k < DM; k += 4) {
        ushort4 wv = *(const ushort4*)(w + k);
        acc += p[k]*us2f(wv.x) + p[k+1]*us2f(wv.y) + p[k+2]*us2f(wv.z) + p[k+3]*us2f(wv.w);
    }
    int o = b*NCLS + n;
    if (flag[0]) ((float*)out)[o] = acc;
    else         ((bf16*)out)[o]  = f2b(acc);
}

// ================================================================ launcher
extern "C" void kernel_launch(void* const* d_in, const int* in_sizes, int n_in,
                              void* d_out, int out_size, void* d_ws, size_t ws_size,
                              hipStream_t stream)
{
    (void)n_in; (void)out_size;
    dim3 blk(256);

    const bool is_f32[21] = { false, false, true, true, true, true, false, true, true,
                              false, false, true,  true, true, true, true, false,
                              true,  true,  false, true };

    size_t off = 0;
    auto carve = [&](size_t bytes) -> void* {
        void* q = (char*)d_ws + off;
        off += (bytes + 255) & ~(size_t)255;
        return q;
    };

    unsigned* flag = (unsigned*)carve(256);
    void* canon[21];
    for (int i = 0; i < 21; ++i)
        canon[i] = carve((size_t)in_sizes[i] * (is_f32[i] ? 4 : 2));

    float* residual = (float*)carve((size_t)M_TOK*DM*4);
    bf16*  hn       = (bf16*) carve((size_t)M_TOK*DM*2);
    float* pooled   = (float*)carve((size_t)BATCH*DM*4);

    const size_t inner1 = 4*(((size_t)SEQ*DI*2 + 255) & ~(size_t)255)
                          + (((size_t)SEQ*80*2 + 255) & ~(size_t)255)
                          + (((size_t)NSEG*DI*DS*4 + 255) & ~(size_t)255)
                          + (((size_t)NSEG*DI*4 + 255) & ~(size_t)255);
    int g = 8;
    while (g > 1 && off + (size_t)g*inner1 > ws_size) g >>= 1;

    bf16*  xh     = (bf16*) carve((size_t)g*SEQ*DI*2);   // also Ap / ybuf
    bf16*  zh     = (bf16*) carve((size_t)g*SEQ*DI*2);
    bf16*  xc     = (bf16*) carve((size_t)g*SEQ*DI*2);
    bf16*  dtb    = (bf16*) carve((size_t)g*SEQ*DI*2);   // also gated
    bf16*  dbc    = (bf16*) carve((size_t)g*SEQ*80*2);
    float* segb   = (float*)carve((size_t)g*NSEG*DI*DS*4);
    float* sumdtb = (float*)carve((size_t)g*NSEG*DI*4);
    bf16* Ap    = xh;
    bf16* ybuf  = xh;
    bf16* gated = dtb;

    detect_dtype<<<1, 64, 0, stream>>>((const unsigned short*)d_in[4], flag);
    for (int i = 0; i < 21; ++i) {
        int n = in_sizes[i];
        int gr = (n + 255)/256;
        if (is_f32[i]) to_f32 <<<gr, blk, 0, stream>>>(flag, d_in[i], (float*)canon[i], n);
        else           to_bf16<<<gr, blk, 0, stream>>>(flag, d_in[i], (bf16*) canon[i], n);
    }

    const bf16*  xin   = (const bf16*) canon[0];
    const bf16*  pw    = (const bf16*) canon[1];
    const float* pb    = (const float*)canon[2];
    const float* chan  = (const float*)canon[3];
    const float* nw    = (const float*)canon[4];
    const float* nb    = (const float*)canon[5];
    const bf16*  ipw   = (const bf16*) canon[6];
    const float* cw    = (const float*)canon[7];
    const float* cb    = (const float*)canon[8];
    const bf16*  xpw   = (const bf16*) canon[9];
    const bf16*  dtw   = (const bf16*) canon[10];
    const float* dtbia = (const float*)canon[11];
    const float* Alog  = (const float*)canon[12];
    const float* Dpar  = (const float*)canon[13];
    const float* snw   = (const float*)canon[14];
    const float* snb   = (const float*)canon[15];
    const bf16*  opw   = (const bf16*) canon[16];
    const float* nfw   = (const float*)canon[17];
    const float* nfb   = (const float*)canon[18];
    const bf16*  hw    = (const bf16*) canon[19];
    const float* hb    = (const float*)canon[20];

    const int MG  = g*SEQ;
    const int GXm = (MG + 127)/128;

    for (int b0 = 0; b0 < BATCH; b0 += g) {
        gather_patches<<<MG, blk, 0, stream>>>(xin, Ap, b0);
        dim3 gr(GXm, DM/128);
        gemm_mfma<<<gr, blk, 0, stream>>>(Ap, 256, pw, 256,
                                          residual + (size_t)b0*SEQ*DM, nullptr, DM,
                                          pb, chan, MG, DM, 256, 3);
    }

    for (int l = 0; l < LAYERS; ++l) {
        ln768<<<M_TOK, blk, 0, stream>>>(residual, nw + l*DM, nb + l*DM, hn);
        for (int b0 = 0; b0 < BATCH; b0 += g) {
            const bf16* hng = hn + (size_t)b0*SEQ*DM;
            {   dim3 gr(GXm, DI/128);   // in_proj halves (MFMA)
                gemm_mfma<<<gr, blk, 0, stream>>>(hng, DM, ipw + (size_t)l*2*DI*DM, DM,
                                                  nullptr, xh, DI, nullptr, nullptr,
                                                  MG, DI, DM, 0);
                gemm_mfma<<<gr, blk, 0, stream>>>(hng, DM, ipw + (size_t)l*2*DI*DM + (size_t)DI*DM, DM,
                                                  nullptr, zh, DI, nullptr, nullptr,
                                                  MG, DI, DM, 0);
            }
            conv_silu<<<(MG*DI)/256, blk, 0, stream>>>(xh, cw + (size_t)l*DI*4, cb + l*DI, xc);
            {   dim3 gr(GXm, 1);        // x_proj (MFMA, N=80 in one 128-tile)
                gemm_mfma<<<gr, blk, 0, stream>>>(xc, DI, xpw + (size_t)l*80*DI, DI,
                                                  nullptr, dbc, 80, nullptr, nullptr,
                                                  MG, 80, DI, 0);
            }
            {   dim3 gr(GXm, DI/128);   // dt_proj + softplus (MFMA, K=48 zero-padded)
                gemm_mfma<<<gr, blk, 0, stream>>>(dbc, 80, dtw + (size_t)l*DI*DTR, DTR,
                                                  nullptr, dtb, DI, dtbia + l*DI, nullptr,
                                                  MG, DI, DTR, 1);
            }
            // chunked scan: summaries -> boundary scan -> within-segment emit
            scan_p1<<<g*(DI/16)*NSEG, dim3(64), 0, stream>>>(dtb, xc, dbc,
                                                             Alog + (size_t)l*DI*DS,
                                                             segb, sumdtb);
            scan_p2<<<g*(DI/16), blk, 0, stream>>>(Alog + (size_t)l*DI*DS, sumdtb, segb);
            scan_p3<<<g*(DI/16)*NSEG, dim3(64), 0, stream>>>(dtb, xc, dbc,
                                                             Alog + (size_t)l*DI*DS,
                                                             Dpar + l*DI, segb, ybuf);
            gate_ln<<<MG, blk, 0, stream>>>(ybuf, zh, snw + l*DI, snb + l*DI, gated);
            {   dim3 gr(GXm, DM/128);   // out_proj += residual (MFMA epi2)
                gemm_mfma<<<gr, blk, 0, stream>>>(gated, DI, opw + (size_t)l*DM*DI, DI,
                                                  residual + (size_t)b0*SEQ*DM, nullptr, DM,
                                                  nullptr, nullptr, MG, DM, DI, 2);
            }
        }
    }

    ln768<<<M_TOK, blk, 0, stream>>>(residual, nfw, nfb, hn);
    pool_kernel<<<(BATCH*DM)/256, blk, 0, stream>>>(hn, pooled);
    head_kernel<<<(BATCH*NCLS + 255)/256, blk, 0, stream>>>(flag, pooled, hw, hb, d_out);
}